// Round 15
// baseline (102.788 us; speedup 1.0000x reference)
//
#include <hip/hip_runtime.h>
#include <hip/hip_bf16.h>

#define EPS 1e-3f

typedef float f32x4 __attribute__((ext_vector_type(4)));
typedef float f4    __attribute__((ext_vector_type(4)));
typedef short short8 __attribute__((ext_vector_type(8)));

__device__ __forceinline__ unsigned short f2bf(float f) {
    unsigned u = __float_as_uint(f);
    u += 0x7FFFu + ((u >> 16) & 1u);   // round-to-nearest-even
    return (unsigned short)(u >> 16);
}
__device__ __forceinline__ float bf2f(unsigned s) {
    return __uint_as_float(s << 16);
}
// packed f32x2 -> bf16x2 (RNE)
__device__ __forceinline__ unsigned pk2(float lo, float hi) {
    float2 t; t.x = lo; t.y = hi;
    __hip_bfloat162 hh = __float22bfloat162_rn(t);
    return *reinterpret_cast<unsigned*>(&hh);
}
// async 16B global -> LDS (no dest VGPR, deep HW queue)
__device__ __forceinline__ void gload_lds16(const void* gsrc, void* ldst) {
    __builtin_amdgcn_global_load_lds(
        (const __attribute__((address_space(1))) void*)gsrc,
        (__attribute__((address_space(3))) void*)ldst,
        16, 0, 0);
}

// ---------------------------------------------------------------------------
// Prep: fold BN1/BN2 into attention weights, transpose all weights to bf16
// ---------------------------------------------------------------------------
__global__ void prep_kernel(const float* __restrict__ w3,
                            const float* __restrict__ g1, const float* __restrict__ be1,
                            const float* __restrict__ m1, const float* __restrict__ v1,
                            const float* __restrict__ wa1, const float* __restrict__ ba1,
                            const float* __restrict__ g2, const float* __restrict__ be2,
                            const float* __restrict__ m2, const float* __restrict__ v2,
                            const float* __restrict__ wa2, const float* __restrict__ ba2,
                            unsigned short* __restrict__ w3T,
                            unsigned short* __restrict__ wa1T,
                            unsigned short* __restrict__ wa2T,
                            float* __restrict__ b_a1p, float* __restrict__ b_a2p)
{
    const int blk = blockIdx.x;
    const int tid = threadIdx.x;
    if (blk < 64) {
        #pragma unroll
        for (int i = 0; i < 4; ++i) {
            int f = blk * 4 + i;
            w3T[f * 256 + tid] = f2bf(w3[tid * 256 + f]);
        }
    } else if (blk < 96) {
        int a = blk - 64;
        int c = tid;
        float s1 = rsqrtf(v1[c] + EPS) * g1[c];
        float wv = wa1[c * 32 + a];
        wa1T[a * 256 + c] = f2bf(wv * s1);
        float part = (be1[c] - m1[c] * s1) * wv;
        __shared__ float red[4];
        #pragma unroll
        for (int off = 32; off > 0; off >>= 1) part += __shfl_down(part, off);
        if ((tid & 63) == 0) red[tid >> 6] = part;
        __syncthreads();
        if (tid == 0) b_a1p[a] = ba1[a] + red[0] + red[1] + red[2] + red[3];
    } else {
        int f = tid;
        float acc = ba2[f];
        #pragma unroll
        for (int a = 0; a < 32; ++a) {
            float s2 = rsqrtf(v2[a] + EPS) * g2[a];
            float wv = wa2[a * 256 + f];
            wa2T[f * 32 + a] = f2bf(wv * s2);
            acc += (be2[a] - m2[a] * s2) * wv;
        }
        b_a2p[f] = acc;
    }
}

// ---------------------------------------------------------------------------
// Kernel A: a1 = relu(x_bn @ wa1') (bf16 ws) + deninv[px] = 1/sum_f e (f32).
// Block = one image row, 4 waves x 16 px, tiny LDS, no barrier. (R13 proven.)
// ---------------------------------------------------------------------------
__global__ __launch_bounds__(256, 8)
void attn1_kernel(const float* __restrict__ x,
                  const unsigned short* __restrict__ wa1T,
                  const unsigned short* __restrict__ wa2T,
                  const float* __restrict__ b_a1p,
                  const float* __restrict__ b_a2p,
                  unsigned short* __restrict__ a1g,
                  float* __restrict__ deninv_g)
{
    __shared__ __align__(16) unsigned char lds[5120];

    const int tid = threadIdx.x;
    const int bid = blockIdx.x;
    const int row = (bid & 7) * 128 + (bid >> 3);   // XCD swizzle

    const int wv   = tid >> 6;
    const int lane = tid & 63;
    const int cl   = lane & 15;
    const int lkg  = lane >> 4;

    const float* xr = x + ((size_t)row * 64 + wv * 16 + cl) * 256;

    f32x4 acc1[2];
    acc1[0] = (f32x4){0,0,0,0};
    acc1[1] = (f32x4){0,0,0,0};
    #pragma unroll
    for (int kk = 0; kk < 8; ++kk) {
        f4 u0 = *(const f4*)(xr + kk * 32 + lkg * 8);
        f4 u1 = *(const f4*)(xr + kk * 32 + lkg * 8 + 4);
        unsigned apv[4];
        apv[0] = pk2(u0.x, u0.y); apv[1] = pk2(u0.z, u0.w);
        apv[2] = pk2(u1.x, u1.y); apv[3] = pk2(u1.z, u1.w);
        short8 afr = *reinterpret_cast<short8*>(apv);
        #pragma unroll
        for (int t = 0; t < 2; ++t) {
            short8 bfr = *(const short8*)(wa1T + ((t * 16 + cl) * 256 + kk * 32 + lkg * 8));
            acc1[t] = __builtin_amdgcn_mfma_f32_16x16x32_bf16(afr, bfr, acc1[t], 0, 0, 0);
        }
    }
    const unsigned a1base = (unsigned)wv * 1280u;
    #pragma unroll
    for (int t = 0; t < 2; ++t) {
        int a = t * 16 + cl;
        float bb = b_a1p[a];
        #pragma unroll
        for (int r = 0; r < 4; ++r) {
            float vv = acc1[t][r] + bb;
            vv = vv > 0.f ? vv : 0.f;
            int m = lkg * 4 + r;
            *(unsigned short*)(lds + a1base + m * 80 + a * 2) = f2bf(vv);
        }
    }
    asm volatile("s_waitcnt lgkmcnt(0)" ::: "memory");
    __builtin_amdgcn_sched_barrier(0);
    uint4 v = *(const uint4*)(lds + a1base + (lane >> 2) * 80 + (lane & 3) * 16);
    *(uint4*)(a1g + (size_t)row * 2048 + wv * 512 + lane * 8) = v;

    // GEMM2 full-f for own 16 px -> deninv (from bf16-rounded a1)
    {
        short8 a1f = *(const short8*)(lds + a1base + cl * 80 + lkg * 16);
        float ssum = 0.f;
        #pragma unroll
        for (int t = 0; t < 16; ++t) {
            short8 wfr = *(const short8*)(wa2T + ((t * 16 + cl) * 32 + lkg * 8));
            f32x4 z = {0, 0, 0, 0};
            f32x4 a2 = __builtin_amdgcn_mfma_f32_16x16x32_bf16(wfr, a1f, z, 0, 0, 0);
            f4 bb = *(const f4*)(b_a2p + t * 16 + lkg * 4);
            float v0 = a2[0] + bb.x; v0 = v0 > 0.f ? v0 : 0.f;
            float v1 = a2[1] + bb.y; v1 = v1 > 0.f ? v1 : 0.f;
            float v2 = a2[2] + bb.z; v2 = v2 > 0.f ? v2 : 0.f;
            float v3 = a2[3] + bb.w; v3 = v3 > 0.f ? v3 : 0.f;
            ssum += (__expf(v0) + __expf(v1)) + (__expf(v2) + __expf(v3));
        }
        ssum += __shfl_xor(ssum, 16);
        ssum += __shfl_xor(ssum, 32);
        if (lkg == 0)
            deninv_g[row * 64 + wv * 16 + cl] = 1.f / ssum;
    }
}

// ---------------------------------------------------------------------------
// Kernel B (v3): block = 2 image rows x full 256 f; 1024 thr / 16 waves;
// grid 512 = 2 exact 1-block/CU rounds.  LDS 128 KB:
//   [0,32768)      xs row0 (3x3 boxsum bf16, XOR-swizzled)
//   [32768,65536)  xs row1
//   [65536,131072) w3T half-buffer [128 f][256 c] bf16, source pre-XOR'd so
//                  swizzled reads are conflict-free (rule: linear dest +
//                  inverse-swizzled source + swizzled read)
// w3T is staged by global_load_lds (async, zero dest VGPRs -> deep MLP);
// half-0 staging overlaps xs compute, half-1 staging overlaps GEMM2-h1.
// The MFMA kk-loop is 100% LDS-fed: zero global loads inside.
// Per wave (ri = wv>>3, q = wv&7): per half, 16-f slice x 64 px of row ri:
// 32 MFMA main + 4 MFMA GEMM2; deninv precomputed by attn1 (no 2nd sync).
// ---------------------------------------------------------------------------
__global__ __launch_bounds__(1024, 4)
void fused2_kernel(const float* __restrict__ x,
                   const unsigned short* __restrict__ a1g,
                   const float* __restrict__ b3,
                   const unsigned short* __restrict__ w3T,
                   const unsigned short* __restrict__ wa2T,
                   const float* __restrict__ b_a2p,
                   const float* __restrict__ deninv_g,
                   float* __restrict__ out)
{
    __shared__ __align__(16) unsigned char lds[131072];

    const int tid = threadIdx.x;
    const int bid = blockIdx.x;
    const int pair = (bid & 7) * 64 + (bid >> 3);   // XCD swizzle (512%8==0)
    const int r0   = pair * 2;
    const int h0   = r0 & 63;

    const int wv   = tid >> 6;
    const int lane = tid & 63;
    const int cl   = lane & 15;
    const int lkg  = lane >> 4;
    const int ri   = wv >> 3;      // which of the 2 rows this wave owns
    const int q    = wv & 7;       // stage strip / f-slice selector
    const int row  = r0 + ri;
    const int h    = h0 + ri;

    // ---- issue w3T half-0 staging (async, 4x16B per thread) ---------------
    #pragma unroll
    for (int i = 0; i < 4; ++i) {
        unsigned Lw = (unsigned)i * 16384u + (unsigned)wv * 1024u;   // wave base
        unsigned L  = Lw + (unsigned)lane * 16u;
        unsigned fl = L >> 9;            // local f row 0..127
        unsigned cbs = L & 511u;
        unsigned csrc = cbs ^ ((fl & 7u) << 4);
        const unsigned short* gs = w3T + (fl << 8) + (csrc >> 1);
        gload_lds16(gs, lds + 65536 + Lw);
    }

    // ---- early register loads (a1 frags, deninv) --------------------------
    const unsigned short* a1row = a1g + (size_t)row * 2048;
    short8 a1b[4];
    #pragma unroll
    for (int pt = 0; pt < 4; ++pt)
        a1b[pt] = *(const short8*)(a1row + ((pt * 16 + cl) * 32 + lkg * 8));
    float isv[4];
    #pragma unroll
    for (int pt = 0; pt < 4; ++pt)
        isv[pt] = deninv_g[row * 64 + pt * 16 + cl];

    // ---- stage xs for own row strip (overlaps w3T half-0 staging) ---------
    {
        const size_t rowb = (size_t)row * 16384;
        const float* xrow = x + rowb;
        const bool hm = (h > 0), hp = (h < 63);
        const f4* pc = (const f4*)xrow;
        const f4* pm = (const f4*)(xrow - 16384);
        const f4* pp = (const f4*)(xrow + 16384);
        const f4 z4 = {0.f, 0.f, 0.f, 0.f};
        f4 lm[10], lc[10], lp[10];
        #pragma unroll
        for (int r = 0; r < 10; ++r) {
            int g  = q * 8 - 1 + r;
            int gc = g < 0 ? 0 : (g > 63 ? 63 : g);
            int idx = gc * 64 + lane;
            lc[r] = pc[idx];
            lm[r] = hm ? pm[idx] : z4;
            lp[r] = hp ? pp[idx] : z4;
        }
        f4 vs[10];
        #pragma unroll
        for (int r = 0; r < 10; ++r) {
            int g = q * 8 - 1 + r;
            f4 v = lm[r] + lc[r] + lp[r];
            vs[r] = (g >= 0 && g < 64) ? v : z4;
        }
        unsigned xsb = (unsigned)ri * 32768u;
        #pragma unroll
        for (int j = 0; j < 8; ++j) {
            f4 s = vs[j] + vs[j + 1] + vs[j + 2];
            int gw = q * 8 + j;               // gw & 7 == j
            unsigned addr = xsb + (unsigned)gw * 512u +
                            (((unsigned)lane * 8u) ^ (((unsigned)j & 7u) << 4));
            uint2 pk;
            pk.x = pk2(s.x, s.y);
            pk.y = pk2(s.z, s.w);
            *(uint2*)(lds + addr) = pk;
        }
    }

    // ---- per-half: GEMM2 -> sync -> main GEMM (LDS-only) -> epilogue ------
    const int rh = (h == 0 || h == 63) ? 2 : 3;
    const size_t orow = (size_t)row * 16384;
    const unsigned xsb  = (unsigned)ri * 32768u;
    const unsigned wrow = (unsigned)(q * 16 + cl);
    const unsigned wbase = 65536u + wrow * 512u;
    const unsigned wswz  = (wrow & 7u) << 4;

    #pragma unroll
    for (int fh = 0; fh < 2; ++fh) {
        const int F0g = fh * 128 + q * 16;

        // GEMM2 slice + exp (register-only; overlaps half-fh staging)
        uint2 ep[4];
        {
            short8 wfr2 = *(const short8*)(wa2T + ((F0g + cl) * 32 + lkg * 8));
            f4 bb2 = *(const f4*)(b_a2p + F0g + lkg * 4);
            #pragma unroll
            for (int pt = 0; pt < 4; ++pt) {
                f32x4 z = {0, 0, 0, 0};
                f32x4 a2 = __builtin_amdgcn_mfma_f32_16x16x32_bf16(wfr2, a1b[pt], z, 0, 0, 0);
                float e0, e1, e2, e3;
                float v0 = a2[0] + bb2.x; v0 = v0 > 0.f ? v0 : 0.f; e0 = __expf(v0);
                float v1 = a2[1] + bb2.y; v1 = v1 > 0.f ? v1 : 0.f; e1 = __expf(v1);
                float v2 = a2[2] + bb2.z; v2 = v2 > 0.f ? v2 : 0.f; e2 = __expf(v2);
                float v3 = a2[3] + bb2.w; v3 = v3 > 0.f ? v3 : 0.f; e3 = __expf(v3);
                ep[pt].x = pk2(e0, e1);
                ep[pt].y = pk2(e2, e3);
            }
        }

        __syncthreads();   // implicit vmcnt(0): w3T half ready (+ xs on fh=0)

        // main GEMM: 16-f slice x 64 px, pure LDS
        f32x4 acc[4];
        #pragma unroll
        for (int pt = 0; pt < 4; ++pt) acc[pt] = (f32x4){0, 0, 0, 0};
        #pragma unroll
        for (int kk = 0; kk < 8; ++kk) {
            unsigned cb = (unsigned)(kk * 64 + lkg * 16);
            short8 wfr = *(const short8*)(lds + wbase + (cb ^ wswz));
            #pragma unroll
            for (int pt = 0; pt < 4; ++pt) {
                unsigned px = (unsigned)(pt * 16 + cl);
                short8 xfr = *(const short8*)(lds + xsb + px * 512u +
                                              (cb ^ ((px & 7u) << 4)));
                acc[pt] = __builtin_amdgcn_mfma_f32_16x16x32_bf16(wfr, xfr, acc[pt], 0, 0, 0);
            }
        }

        // epilogue: o = e * deninv * (s + cnt*b3)
        f4 b3v = *(const f4*)(b3 + F0g + lkg * 4);
        #pragma unroll
        for (int pt = 0; pt < 4; ++pt) {
            int px = pt * 16 + cl;
            float is = isv[pt];
            float cnt = (float)(rh * ((px == 0 || px == 63) ? 2 : 3));
            uint2 ev = ep[pt];
            f4 o;
            o.x = bf2f(ev.x & 0xffffu) * is * (acc[pt][0] + cnt * b3v.x);
            o.y = bf2f(ev.x >> 16)     * is * (acc[pt][1] + cnt * b3v.y);
            o.z = bf2f(ev.y & 0xffffu) * is * (acc[pt][2] + cnt * b3v.z);
            o.w = bf2f(ev.y >> 16)     * is * (acc[pt][3] + cnt * b3v.w);
            *(f4*)(out + orow + (size_t)px * 256 + F0g + lkg * 4) = o;
        }

        __syncthreads();   // all reads of w3T buffer done

        if (fh == 0) {
            // issue half-1 staging (async; overlaps next GEMM2)
            #pragma unroll
            for (int i = 0; i < 4; ++i) {
                unsigned Lw = (unsigned)i * 16384u + (unsigned)wv * 1024u;
                unsigned L  = Lw + (unsigned)lane * 16u;
                unsigned fl = L >> 9;
                unsigned cbs = L & 511u;
                unsigned csrc = cbs ^ ((fl & 7u) << 4);
                const unsigned short* gs = w3T + ((128u + fl) << 8) + (csrc >> 1);
                gload_lds16(gs, lds + 65536 + Lw);
            }
        }
    }
}

extern "C" void kernel_launch(void* const* d_in, const int* in_sizes, int n_in,
                              void* d_out, int out_size, void* d_ws, size_t ws_size,
                              hipStream_t stream)
{
    const float* x   = (const float*)d_in[0];
    const float* w3  = (const float*)d_in[1];
    const float* b3  = (const float*)d_in[2];
    const float* g1  = (const float*)d_in[3];
    const float* be1 = (const float*)d_in[4];
    const float* m1  = (const float*)d_in[5];
    const float* v1  = (const float*)d_in[6];
    const float* wa1 = (const float*)d_in[7];
    const float* ba1 = (const float*)d_in[8];
    const float* g2  = (const float*)d_in[9];
    const float* be2 = (const float*)d_in[10];
    const float* m2  = (const float*)d_in[11];
    const float* v2  = (const float*)d_in[12];
    const float* wa2 = (const float*)d_in[13];
    const float* ba2 = (const float*)d_in[14];

    unsigned char* ws = (unsigned char*)d_ws;
    unsigned short* w3T    = (unsigned short*)(ws);
    unsigned short* wa1T   = (unsigned short*)(ws + 131072);
    unsigned short* wa2T   = (unsigned short*)(ws + 147456);
    float*          b_a1p  = (float*)(ws + 163840);
    float*          b_a2p  = (float*)(ws + 163968);
    unsigned short* a1g    = (unsigned short*)(ws + 196608);             // 4 MB
    float*          deninv = (float*)(ws + 196608 + 4194304);            // 256 KB

    hipLaunchKernelGGL(prep_kernel, dim3(97), dim3(256), 0, stream,
                       w3, g1, be1, m1, v1, wa1, ba1, g2, be2, m2, v2, wa2, ba2,
                       w3T, wa1T, wa2T, b_a1p, b_a2p);
    hipLaunchKernelGGL(attn1_kernel, dim3(1024), dim3(256), 0, stream,
                       x, wa1T, wa2T, b_a1p, b_a2p, a1g, deninv);
    hipLaunchKernelGGL(fused2_kernel, dim3(512), dim3(1024), 0, stream,
                       x, a1g, b3, w3T, wa2T, b_a2p, deninv, (float*)d_out);
}